// Round 7
// baseline (278.902 us; speedup 1.0000x reference)
//
#include <hip/hip_runtime.h>
#include <hip/hip_bf16.h>

#define NN 100000   // nodes
#define FF 10       // input features
#define HH 20       // hidden dim
#define GG 512      // graphs
#define LL 2        // labels

#define NB 500      // dst buckets
#define BNODES 200  // nodes per bucket (NN / NB)
#define CAP 7168    // per-bucket capacity (mean 6400, ~9.6 sigma)
#define HB 100      // nodes per half-bucket (one layer block)
#define SCAP 3712   // per-half-bucket edge capacity (mean 3200, ~9 sigma)
#define TILE 4096   // edges per block in multisplit
#define SRC_BITS 17
#define SRC_MASK 0x1FFFFu

// Split-aligned feature layout (same total footprint as unpadded):
//  x:  xA[N][8]  16B rows (1 uint4 lane)  + xB[N][2] 4B rows (1 u32 lane)
//  h:  hA[N][16] 32B rows (2 uint4 lanes) + hB[N][4] 8B rows (1 uint2 lane)
// -> 2 (layer1) / 3 (layers 2,3) lane-requests per edge instead of 5,
//    every load naturally aligned (16B/8B/4B).

// bf16 helpers (storage-only; all math in f32)
__device__ inline unsigned short f2bf(float f) {
  unsigned u = __float_as_uint(f);
  unsigned r = u + 0x7FFFu + ((u >> 16) & 1u);
  return (unsigned short)(r >> 16);
}
__device__ inline float bflo(unsigned u) { return __uint_as_float(u << 16); }
__device__ inline float bfhi(unsigned u) { return __uint_as_float(u & 0xFFFF0000u); }

// ---------------------------------------------------------------------------
// Cast x f32->bf16 into split xA/xB and zero cursors/pool accums.
// ---------------------------------------------------------------------------
__global__ __launch_bounds__(256) void cast_init_kernel(
    const float* __restrict__ x, unsigned short* __restrict__ xA,
    unsigned short* __restrict__ xB,
    float* __restrict__ sump, int* __restrict__ maxp, float* __restrict__ cnt,
    int* __restrict__ cursor, int n_nodes) {
  int i = blockIdx.x * 256 + threadIdx.x;
  if (i < n_nodes * 8) {
    int node = i >> 3;
    int f = i & 7;
    xA[i] = f2bf(__builtin_nontemporal_load(x + (size_t)node * FF + f));
  }
  if (i < n_nodes * 2) {
    int node = i >> 1;
    int f = i & 1;
    xB[i] = f2bf(__builtin_nontemporal_load(x + (size_t)node * FF + 8 + f));
  }
  if (i < GG * HH) {
    sump[i] = 0.0f;
    maxp[i] = 0;
  }
  if (i < GG) cnt[i] = 0.0f;
  if (i < NB) cursor[i] = 0;
}

// ---------------------------------------------------------------------------
// Multisplit (512 thr) with LDS-staged COALESCED writes into fixed-CAP bucket
// regions. Payload pack: (local_dst << 17) | src.   (unchanged from r0)
// ---------------------------------------------------------------------------
__global__ __launch_bounds__(512) void multisplit_kernel(
    const int* __restrict__ src, const int* __restrict__ dst,
    int* __restrict__ cursor, unsigned int* __restrict__ pay, int E) {
  __shared__ int lhist[NB];
  __shared__ int lofs[NB];
  __shared__ int gbase[NB];
  __shared__ int lcur[NB];
  __shared__ unsigned int sord[TILE];
  __shared__ unsigned short sdbk[TILE];
  __shared__ int ss[512];
  int t = threadIdx.x;
  if (t < NB) lhist[t] = 0;
  __syncthreads();

  int base = blockIdx.x * TILE;
  int count = E - base;
  if (count > TILE) count = TILE;

  for (int i = t; i < count; i += 512)
    atomicAdd(&lhist[dst[base + i] / BNODES], 1);
  __syncthreads();

  int own = (t < NB) ? lhist[t] : 0;
  ss[t] = own;
  __syncthreads();
  for (int off = 1; off < 512; off <<= 1) {
    int a0 = (t >= off) ? ss[t - off] : 0;
    __syncthreads();
    ss[t] += a0;
    __syncthreads();
  }
  if (t < NB) {
    lofs[t] = ss[t] - own;
    int bo = own ? atomicAdd(&cursor[t], own) : 0;
    if (bo > CAP - own) bo = CAP - own;
    gbase[t] = t * CAP + bo;
    lcur[t] = 0;
  }
  __syncthreads();

  for (int i = t; i < count; i += 512) {
    int e = base + i;
    int d = __builtin_nontemporal_load(dst + e);
    int s = __builtin_nontemporal_load(src + e);
    int bk = d / BNODES;
    int ld = d - bk * BNODES;
    int r = atomicAdd(&lcur[bk], 1);
    int slot = lofs[bk] + r;
    sord[slot] = ((unsigned)ld << SRC_BITS) | (unsigned)s;
    sdbk[slot] = (unsigned short)bk;
  }
  __syncthreads();

  for (int i = t; i < count; i += 512) {
    int bk = sdbk[i];
    pay[gbase[bk] + (i - lofs[bk])] = sord[i];
  }
}

// ---------------------------------------------------------------------------
// One-time CSR finalize (unchanged from r0).
// ---------------------------------------------------------------------------
__global__ __launch_bounds__(256) void bucket_csr_kernel(
    const unsigned int* __restrict__ pay, const int* __restrict__ cursor,
    int* __restrict__ srt, int* __restrict__ rofs, int* __restrict__ rend) {
  __shared__ int lhist[BNODES];
  __shared__ int lofs[BNODES];
  __shared__ int lcur[BNODES];
  __shared__ int ss[256];
  int b = blockIdx.x;
  int t = threadIdx.x;
  int k0 = b * CAP;
  int ecnt = cursor[b];
  if (ecnt > CAP) ecnt = CAP;

  if (t < BNODES) lhist[t] = 0;
  __syncthreads();
  for (int k = t; k < ecnt; k += 256)
    atomicAdd(&lhist[pay[k0 + k] >> SRC_BITS], 1);
  __syncthreads();

  int own = (t < BNODES) ? lhist[t] : 0;
  ss[t] = own;
  __syncthreads();
  for (int off = 1; off < 256; off <<= 1) {
    int a0 = (t >= off) ? ss[t - off] : 0;
    __syncthreads();
    ss[t] += a0;
    __syncthreads();
  }
  if (t < BNODES) {
    int ex = ss[t] - own;
    lofs[t] = ex;
    lcur[t] = 0;
    rofs[b * BNODES + t] = k0 + ex;
    rend[b * BNODES + t] = k0 + ex + own;
  }
  __syncthreads();

  for (int k = t; k < ecnt; k += 256) {
    unsigned p = pay[k0 + k];
    int ld = p >> SRC_BITS;
    int r = atomicAdd(&lcur[ld], 1);
    srt[k0 + lofs[ld] + r] = (int)(p & SRC_MASK);
  }
}

// ---------------------------------------------------------------------------
// Fused HALF-bucket layer (r0 structure; only the gather's load shape and
// array layout changed): split-aligned inputs, A-gather and B-gather on
// DISJOINT WAVES (A: t<HB*ALN, B: t in [256,256+HB)), 2x-unrolled loops.
// DIN=10: A=1 uint4 lane/node, B=1 u32 lane.  DIN=20: A=2 uint4, B=1 uint2.
// ---------------------------------------------------------------------------
template<int DIN>
__global__ __launch_bounds__(512, 8) void bucket_layer_kernel(
    const unsigned short* __restrict__ hA, const unsigned short* __restrict__ hB,
    const int* __restrict__ srt,
    const int* __restrict__ rofs, const int* __restrict__ rend,
    const float* __restrict__ Wrel, const float* __restrict__ bias,
    const float* __restrict__ Wroot,
    unsigned short* __restrict__ oA, unsigned short* __restrict__ oB) {
  constexpr int AST = DIN + 1;
  constexpr int AW = (DIN == 10) ? 8 : 16;   // A elems per row
  constexpr int ALN = AW / 8;                // A lanes per node
  __shared__ int sSrc[SCAP];
  __shared__ float acc[HB * AST];
  __shared__ unsigned roots32[HB * DIN / 2];
  __shared__ float sWrel[DIN * HH];
  __shared__ float sWroot[DIN * HH];
  __shared__ float sb[HH];
  __shared__ int sRofs[HB];
  __shared__ int sRend[HB];
  __shared__ int sSeg0, sSegLen;
  int b2 = blockIdx.x;
  int t = threadIdx.x;
  int nbase = b2 * HB;

  for (int i = t; i < DIN * HH; i += 512) {
    sWrel[i] = Wrel[i];
    sWroot[i] = Wroot[i];
  }
  if (t < HH) sb[t] = bias[t];
  if (t < HB) {
    sRofs[t] = rofs[nbase + t];
    sRend[t] = rend[nbase + t];
  }
  if (t == 0) {
    int s0 = rofs[nbase];
    int sl = rend[nbase + HB - 1] - s0;
    sSeg0 = s0;
    sSegLen = sl < SCAP ? sl : SCAP;
  }
  // roots: contiguous u32 copies from both split arrays
  {
    const unsigned* rsA = (const unsigned*)(hA + (size_t)nbase * AW);
    for (int i = t; i < HB * (AW / 2); i += 512) {
      int ln = i / (AW / 2);
      int p = i - ln * (AW / 2);
      roots32[ln * (DIN / 2) + p] = rsA[i];
    }
    const unsigned* rsB = (const unsigned*)(hB + (size_t)nbase * (DIN - AW));
    for (int i = t; i < HB * ((DIN - AW) / 2); i += 512) {
      int ln = i / ((DIN - AW) / 2);
      int p = i - ln * ((DIN - AW) / 2);
      roots32[ln * (DIN / 2) + AW / 2 + p] = rsB[i];
    }
  }
  __syncthreads();

  int seg0 = sSeg0, seglen = sSegLen;
  for (int i = t; i < seglen; i += 512) sSrc[i] = srt[seg0 + i];
  __syncthreads();

  // ---- A-gather: waves 0..(ALN*HB/64) ----
  if (t < HB * ALN) {
    int ln = t / ALN;
    int c = t - ln * ALN;
    int k0 = sRofs[ln] - seg0;
    int k1 = sRend[ln] - seg0;
    if (k1 > seglen) k1 = seglen;  // >9-sigma clamp, never in practice
    const unsigned short* bp = hA + c * 8;
    float a0 = 0, a1 = 0, a2 = 0, a3 = 0, a4 = 0, a5 = 0, a6 = 0, a7 = 0;
    int k = k0;
    for (; k + 1 < k1; k += 2) {
      uint4 u = *(const uint4*)(bp + (size_t)sSrc[k] * AW);
      uint4 v = *(const uint4*)(bp + (size_t)sSrc[k + 1] * AW);
      a0 += bflo(u.x); a1 += bfhi(u.x);
      a2 += bflo(u.y); a3 += bfhi(u.y);
      a4 += bflo(u.z); a5 += bfhi(u.z);
      a6 += bflo(u.w); a7 += bfhi(u.w);
      a0 += bflo(v.x); a1 += bfhi(v.x);
      a2 += bflo(v.y); a3 += bfhi(v.y);
      a4 += bflo(v.z); a5 += bfhi(v.z);
      a6 += bflo(v.w); a7 += bfhi(v.w);
    }
    if (k < k1) {
      uint4 u = *(const uint4*)(bp + (size_t)sSrc[k] * AW);
      a0 += bflo(u.x); a1 += bfhi(u.x);
      a2 += bflo(u.y); a3 += bfhi(u.y);
      a4 += bflo(u.z); a5 += bfhi(u.z);
      a6 += bflo(u.w); a7 += bfhi(u.w);
    }
    float* ap = acc + ln * AST + c * 8;
    ap[0] = a0; ap[1] = a1; ap[2] = a2; ap[3] = a3;
    ap[4] = a4; ap[5] = a5; ap[6] = a6; ap[7] = a7;
  }

  // ---- B-gather: waves 4.. (disjoint from A's waves) ----
  if (t >= 256 && t < 256 + HB) {
    int ln = t - 256;
    int k0 = sRofs[ln] - seg0;
    int k1 = sRend[ln] - seg0;
    if (k1 > seglen) k1 = seglen;
    if (DIN == 20) {
      float a0 = 0, a1 = 0, a2 = 0, a3 = 0;
      int k = k0;
      for (; k + 1 < k1; k += 2) {
        uint2 u = *(const uint2*)(hB + (size_t)sSrc[k] * 4);
        uint2 v = *(const uint2*)(hB + (size_t)sSrc[k + 1] * 4);
        a0 += bflo(u.x); a1 += bfhi(u.x);
        a2 += bflo(u.y); a3 += bfhi(u.y);
        a0 += bflo(v.x); a1 += bfhi(v.x);
        a2 += bflo(v.y); a3 += bfhi(v.y);
      }
      if (k < k1) {
        uint2 u = *(const uint2*)(hB + (size_t)sSrc[k] * 4);
        a0 += bflo(u.x); a1 += bfhi(u.x);
        a2 += bflo(u.y); a3 += bfhi(u.y);
      }
      float* ap = acc + ln * AST + 16;
      ap[0] = a0; ap[1] = a1; ap[2] = a2; ap[3] = a3;
    } else {
      float a0 = 0, a1 = 0;
      int k = k0;
      for (; k + 1 < k1; k += 2) {
        unsigned u = *(const unsigned*)(hB + (size_t)sSrc[k] * 2);
        unsigned v = *(const unsigned*)(hB + (size_t)sSrc[k + 1] * 2);
        a0 += bflo(u) + bflo(v);
        a1 += bfhi(u) + bfhi(v);
      }
      if (k < k1) {
        unsigned u = *(const unsigned*)(hB + (size_t)sSrc[k] * 2);
        a0 += bflo(u); a1 += bfhi(u);
      }
      float* ap = acc + ln * AST + 8;
      ap[0] = a0; ap[1] = a1;
    }
  }
  __syncthreads();

  // ---- dense (r0 structure), split output writes ----
  for (int idx = t; idx < HB * HH; idx += 512) {
    int ln = idx / HH;
    int j = idx - ln * HH;
    const float* a = acc + ln * AST;
    const unsigned short* r = (const unsigned short*)(roots32 + ln * (DIN / 2));
    float v = sb[j];
#pragma unroll
    for (int f = 0; f < DIN; f++) {
      v += a[f] * sWrel[f * HH + j];
      v += bflo((unsigned)r[f]) * sWroot[f * HH + j];
    }
    unsigned short hv = f2bf(fmaxf(v, 0.0f));
    if (j < 16) oA[(size_t)(nbase + ln) * 16 + j] = hv;
    else        oB[(size_t)(nbase + ln) * 4 + (j - 16)] = hv;
  }
}

// ---------------------------------------------------------------------------
// Layer 3 + pooling (r0 structure; split-aligned gather as above):
// dense into registers then written over acc (dead), then block-local pool +
// few global atomics. Post-ReLU >= 0 -> int atomicMax order-correct.
// ---------------------------------------------------------------------------
__global__ __launch_bounds__(512, 8) void bucket_layer_pool_kernel(
    const unsigned short* __restrict__ hA, const unsigned short* __restrict__ hB,
    const int* __restrict__ srt,
    const int* __restrict__ rofs, const int* __restrict__ rend,
    const float* __restrict__ Wrel, const float* __restrict__ bias,
    const float* __restrict__ Wroot, const int* __restrict__ batch,
    float* __restrict__ sump, int* __restrict__ maxp,
    float* __restrict__ cnt) {
  constexpr int DIN = 20;
  constexpr int AST = 21;
  __shared__ int sSrc[SCAP];
  __shared__ float acc[HB * AST];
  __shared__ unsigned roots32[HB * 10];
  __shared__ int sBatch[HB];
  __shared__ float sWrel[DIN * HH];
  __shared__ float sWroot[DIN * HH];
  __shared__ float sb[HH];
  __shared__ int sRofs[HB];
  __shared__ int sRend[HB];
  __shared__ int sSeg0, sSegLen;
  int b2 = blockIdx.x;
  int t = threadIdx.x;
  int nbase = b2 * HB;

  for (int i = t; i < DIN * HH; i += 512) {
    sWrel[i] = Wrel[i];
    sWroot[i] = Wroot[i];
  }
  if (t < HH) sb[t] = bias[t];
  if (t < HB) {
    sRofs[t] = rofs[nbase + t];
    sRend[t] = rend[nbase + t];
    sBatch[t] = batch[nbase + t];
  }
  if (t == 0) {
    int s0 = rofs[nbase];
    int sl = rend[nbase + HB - 1] - s0;
    sSeg0 = s0;
    sSegLen = sl < SCAP ? sl : SCAP;
  }
  {
    const unsigned* rsA = (const unsigned*)(hA + (size_t)nbase * 16);
    for (int i = t; i < HB * 8; i += 512) {
      int ln = i / 8;
      int p = i - ln * 8;
      roots32[ln * 10 + p] = rsA[i];
    }
    const unsigned* rsB = (const unsigned*)(hB + (size_t)nbase * 4);
    for (int i = t; i < HB * 2; i += 512) {
      int ln = i / 2;
      int p = i - ln * 2;
      roots32[ln * 10 + 8 + p] = rsB[i];
    }
  }
  __syncthreads();

  int seg0 = sSeg0, seglen = sSegLen;
  for (int i = t; i < seglen; i += 512) sSrc[i] = srt[seg0 + i];
  __syncthreads();

  // ---- A-gather (waves 0..3) ----
  if (t < HB * 2) {
    int ln = t / 2;
    int c = t - ln * 2;
    int k0 = sRofs[ln] - seg0;
    int k1 = sRend[ln] - seg0;
    if (k1 > seglen) k1 = seglen;
    const unsigned short* bp = hA + c * 8;
    float a0 = 0, a1 = 0, a2 = 0, a3 = 0, a4 = 0, a5 = 0, a6 = 0, a7 = 0;
    int k = k0;
    for (; k + 1 < k1; k += 2) {
      uint4 u = *(const uint4*)(bp + (size_t)sSrc[k] * 16);
      uint4 v = *(const uint4*)(bp + (size_t)sSrc[k + 1] * 16);
      a0 += bflo(u.x); a1 += bfhi(u.x);
      a2 += bflo(u.y); a3 += bfhi(u.y);
      a4 += bflo(u.z); a5 += bfhi(u.z);
      a6 += bflo(u.w); a7 += bfhi(u.w);
      a0 += bflo(v.x); a1 += bfhi(v.x);
      a2 += bflo(v.y); a3 += bfhi(v.y);
      a4 += bflo(v.z); a5 += bfhi(v.z);
      a6 += bflo(v.w); a7 += bfhi(v.w);
    }
    if (k < k1) {
      uint4 u = *(const uint4*)(bp + (size_t)sSrc[k] * 16);
      a0 += bflo(u.x); a1 += bfhi(u.x);
      a2 += bflo(u.y); a3 += bfhi(u.y);
      a4 += bflo(u.z); a5 += bfhi(u.z);
      a6 += bflo(u.w); a7 += bfhi(u.w);
    }
    float* ap = acc + ln * AST + c * 8;
    ap[0] = a0; ap[1] = a1; ap[2] = a2; ap[3] = a3;
    ap[4] = a4; ap[5] = a5; ap[6] = a6; ap[7] = a7;
  }

  // ---- B-gather (waves 4..) ----
  if (t >= 256 && t < 256 + HB) {
    int ln = t - 256;
    int k0 = sRofs[ln] - seg0;
    int k1 = sRend[ln] - seg0;
    if (k1 > seglen) k1 = seglen;
    float a0 = 0, a1 = 0, a2 = 0, a3 = 0;
    int k = k0;
    for (; k + 1 < k1; k += 2) {
      uint2 u = *(const uint2*)(hB + (size_t)sSrc[k] * 4);
      uint2 v = *(const uint2*)(hB + (size_t)sSrc[k + 1] * 4);
      a0 += bflo(u.x); a1 += bfhi(u.x);
      a2 += bflo(u.y); a3 += bfhi(u.y);
      a0 += bflo(v.x); a1 += bfhi(v.x);
      a2 += bflo(v.y); a3 += bfhi(v.y);
    }
    if (k < k1) {
      uint2 u = *(const uint2*)(hB + (size_t)sSrc[k] * 4);
      a0 += bflo(u.x); a1 += bfhi(u.x);
      a2 += bflo(u.y); a3 += bfhi(u.y);
    }
    float* ap = acc + ln * AST + 16;
    ap[0] = a0; ap[1] = a1; ap[2] = a2; ap[3] = a3;
  }
  __syncthreads();

  // ---- dense into registers (acc still needed as input) ----
  float vreg[4];
#pragma unroll
  for (int u = 0; u < 4; u++) {
    int idx = t + u * 512;
    if (idx < HB * HH) {
      int ln = idx / HH;
      int j = idx - ln * HH;
      const float* a = acc + ln * AST;
      const unsigned short* r = (const unsigned short*)(roots32 + ln * 10);
      float v = sb[j];
#pragma unroll
      for (int f = 0; f < DIN; f++) {
        v += a[f] * sWrel[f * HH + j];
        v += bflo((unsigned)r[f]) * sWroot[f * HH + j];
      }
      vreg[u] = fmaxf(v, 0.0f);
    }
  }
  __syncthreads();
#pragma unroll
  for (int u = 0; u < 4; u++) {
    int idx = t + u * 512;
    if (idx < HB * HH) {
      int ln = idx / HH;
      int j = idx - ln * HH;
      acc[ln * AST + j] = vreg[u];
    }
  }
  __syncthreads();

  int g0 = sBatch[0];
  int g1 = sBatch[HB - 1];
  int ngr = g1 - g0 + 1;
  for (int it = t; it < ngr * HH; it += 512) {
    int gi = it / HH;
    int j = it - gi * HH;
    int g = g0 + gi;
    float s = 0.0f, m = 0.0f;
    int c = 0;
    for (int ln = 0; ln < HB; ln++) {
      if (sBatch[ln] == g) {
        float v = acc[ln * AST + j];
        s += v;
        m = fmaxf(m, v);
        c++;
      }
    }
    if (c) {
      atomicAdd(&sump[g * HH + j], s);
      atomicMax(&maxp[g * HH + j], __float_as_int(m));
      if (j == 0) atomicAdd(&cnt[g], (float)c);
    }
  }
}

__global__ __launch_bounds__(256) void readout_kernel(
    const float* __restrict__ sump, const int* __restrict__ maxp,
    const float* __restrict__ cnt, const float* __restrict__ Wlin,
    const float* __restrict__ blin, float* __restrict__ out) {
  int idx = blockIdx.x * 256 + threadIdx.x;
  if (idx >= GG * LL) return;
  int g = idx / LL;
  int l = idx - g * LL;
  float c = cnt[g];
  float inv = 1.0f / fmaxf(c, 1.0f);
  float acc = blin[l];
#pragma unroll
  for (int j = 0; j < HH; j++) {
    float mx = __int_as_float(maxp[g * HH + j]);
    float mean = sump[g * HH + j] * inv;
    acc += mx * Wlin[j * LL + l];
    acc += mean * Wlin[(HH + j) * LL + l];
  }
  out[idx] = acc;
}

extern "C" void kernel_launch(void* const* d_in, const int* in_sizes, int n_in,
                              void* d_out, int out_size, void* d_ws,
                              size_t ws_size, hipStream_t stream) {
  const float* x = (const float*)d_in[0];
  const int* edge_index = (const int*)d_in[1];
  const int* batch = (const int*)d_in[2];
  const float* W_rel1 = (const float*)d_in[3];
  const float* b1 = (const float*)d_in[4];
  const float* W_root1 = (const float*)d_in[5];
  const float* W_rel2 = (const float*)d_in[6];
  const float* b2 = (const float*)d_in[7];
  const float* W_root2 = (const float*)d_in[8];
  const float* W_rel3 = (const float*)d_in[9];
  const float* b3 = (const float*)d_in[10];
  const float* W_root3 = (const float*)d_in[11];
  const float* W_lin = (const float*)d_in[12];
  const float* b_lin = (const float*)d_in[13];
  float* out = (float*)d_out;

  const int E = in_sizes[1] / 2;
  const int n_nodes = in_sizes[0] / FF;  // == NN
  const int* src = edge_index;
  const int* dst = edge_index + E;

  // Workspace layout (16B-aligned chunks)
  unsigned int* pay = (unsigned int*)d_ws;       // NB*CAP u32 (14.3MB)
  int* srt = (int*)(pay + (size_t)NB * CAP);     // NB*CAP (14.3MB)
  int* rofs = srt + (size_t)NB * CAP;            // NN
  int* rend = rofs + NN;                         // NN
  int* cursor = rend + NN;                       // 512
  float* sump = (float*)(cursor + 512);          // GG*HH
  int* maxp = (int*)(sump + GG * HH);            // GG*HH
  float* cnt = (float*)(maxp + GG * HH);         // 512
  unsigned short* xA = (unsigned short*)(cnt + 512);  // NN*8 (1.6MB)
  unsigned short* xB = xA + (size_t)NN * 8;      // NN*2 (0.4MB)
  unsigned short* h1A = xB + (size_t)NN * 2;     // NN*16 (3.2MB)
  unsigned short* h1B = h1A + (size_t)NN * 16;   // NN*4 (0.8MB)
  unsigned short* h2A = h1B + (size_t)NN * 4;    // NN*16 (3.2MB)
  unsigned short* h2B = h2A + (size_t)NN * 16;   // NN*4 (0.8MB)

  const int edge_tiles = (E + TILE - 1) / TILE;

  // ---- Cast x to split bf16 + zero cursors/pool accumulators ----
  cast_init_kernel<<<(n_nodes * 8 + 255) / 256, 256, 0, stream>>>(
      x, xA, xB, sump, maxp, cnt, cursor, n_nodes);

  // ---- Edge partition + one-time CSR build ----
  multisplit_kernel<<<edge_tiles, 512, 0, stream>>>(src, dst, cursor, pay, E);
  bucket_csr_kernel<<<NB, 256, 0, stream>>>(pay, cursor, srt, rofs, rend);

  // ---- Fused per-half-bucket layers (split-aligned gather) ----
  bucket_layer_kernel<FF><<<NB * 2, 512, 0, stream>>>(
      xA, xB, srt, rofs, rend, W_rel1, b1, W_root1, h1A, h1B);
  bucket_layer_kernel<HH><<<NB * 2, 512, 0, stream>>>(
      h1A, h1B, srt, rofs, rend, W_rel2, b2, W_root2, h2A, h2B);
  bucket_layer_pool_kernel<<<NB * 2, 512, 0, stream>>>(
      h2A, h2B, srt, rofs, rend, W_rel3, b3, W_root3, batch, sump, maxp, cnt);

  // ---- Readout ----
  readout_kernel<<<(GG * LL + 255) / 256, 256, 0, stream>>>(
      sump, maxp, cnt, W_lin, b_lin, out);
}

// Round 8
// 248.530 us; speedup vs baseline: 1.1222x; 1.1222x over previous
//
#include <hip/hip_runtime.h>
#include <hip/hip_bf16.h>

#define NN 100000   // nodes
#define FF 10       // input features
#define HH 20       // hidden dim
#define GG 512      // graphs
#define LL 2        // labels

#define NB 500      // dst buckets
#define BNODES 200  // nodes per bucket (NN / NB)
#define CAP 7168    // per-bucket capacity (mean 6400, ~9.6 sigma)
#define HB 100      // nodes per half-bucket (one layer block)
#define SCAP 3712   // per-half-bucket edge capacity (mean 3200, ~9 sigma)
#define TILE 4096   // edges per block in multisplit
#define SRC_BITS 17
#define SRC_MASK 0x1FFFFu

// bf16 helpers (storage-only; all math in f32)
__device__ inline unsigned short f2bf(float f) {
  unsigned u = __float_as_uint(f);
  unsigned r = u + 0x7FFFu + ((u >> 16) & 1u);
  return (unsigned short)(r >> 16);
}
__device__ inline float bflo(unsigned u) { return __uint_as_float(u << 16); }
__device__ inline float bfhi(unsigned u) { return __uint_as_float(u & 0xFFFF0000u); }

// ---------------------------------------------------------------------------
// Cast x f32->bf16 (nt reads; x touched once) and zero cursors/pool accums.
// ---------------------------------------------------------------------------
__global__ __launch_bounds__(256) void cast_init_kernel(
    const float* __restrict__ x, unsigned short* __restrict__ xb,
    float* __restrict__ sump, int* __restrict__ maxp, float* __restrict__ cnt,
    int* __restrict__ cursor, int n) {
  int i = blockIdx.x * 256 + threadIdx.x;
  if (i < n) xb[i] = f2bf(__builtin_nontemporal_load(x + i));
  if (i < GG * HH) {
    sump[i] = 0.0f;
    maxp[i] = 0;
  }
  if (i < GG) cnt[i] = 0.0f;
  if (i < NB) cursor[i] = 0;
}

// ---------------------------------------------------------------------------
// Multisplit (512 thr) with LDS-staged COALESCED writes into fixed-CAP bucket
// regions. Payload pack: (local_dst << 17) | src.
// ---------------------------------------------------------------------------
__global__ __launch_bounds__(512) void multisplit_kernel(
    const int* __restrict__ src, const int* __restrict__ dst,
    int* __restrict__ cursor, unsigned int* __restrict__ pay, int E) {
  __shared__ int lhist[NB];
  __shared__ int lofs[NB];
  __shared__ int gbase[NB];
  __shared__ int lcur[NB];
  __shared__ unsigned int sord[TILE];
  __shared__ unsigned short sdbk[TILE];
  __shared__ int ss[512];
  int t = threadIdx.x;
  if (t < NB) lhist[t] = 0;
  __syncthreads();

  int base = blockIdx.x * TILE;
  int count = E - base;
  if (count > TILE) count = TILE;

  for (int i = t; i < count; i += 512)
    atomicAdd(&lhist[dst[base + i] / BNODES], 1);
  __syncthreads();

  // exclusive scan of lhist (NB=500), 1 elem/thread
  int own = (t < NB) ? lhist[t] : 0;
  ss[t] = own;
  __syncthreads();
  for (int off = 1; off < 512; off <<= 1) {
    int a0 = (t >= off) ? ss[t - off] : 0;
    __syncthreads();
    ss[t] += a0;
    __syncthreads();
  }
  // reserve global ranges (clamped: >9-sigma overflow drops edges, no OOB)
  if (t < NB) {
    lofs[t] = ss[t] - own;
    int bo = own ? atomicAdd(&cursor[t], own) : 0;
    if (bo > CAP - own) bo = CAP - own;
    gbase[t] = t * CAP + bo;
    lcur[t] = 0;
  }
  __syncthreads();

  // pass 2: rank + scatter into bucket-grouped LDS order
  for (int i = t; i < count; i += 512) {
    int e = base + i;
    int d = __builtin_nontemporal_load(dst + e);
    int s = __builtin_nontemporal_load(src + e);
    int bk = d / BNODES;
    int ld = d - bk * BNODES;
    int r = atomicAdd(&lcur[bk], 1);
    int slot = lofs[bk] + r;
    sord[slot] = ((unsigned)ld << SRC_BITS) | (unsigned)s;
    sdbk[slot] = (unsigned short)bk;
  }
  __syncthreads();

  // coalesced run writes
  for (int i = t; i < count; i += 512) {
    int bk = sdbk[i];
    pay[gbase[bk] + (i - lofs[bk])] = sord[i];
  }
}

// ---------------------------------------------------------------------------
// One-time CSR finalize: per bucket, sort pay run by local node into global
// srt (same fixed-CAP region, so each half-bucket's segment is contiguous),
// and write absolute rofs/rend per node. Writes confined to own region.
// ---------------------------------------------------------------------------
__global__ __launch_bounds__(256) void bucket_csr_kernel(
    const unsigned int* __restrict__ pay, const int* __restrict__ cursor,
    int* __restrict__ srt, int* __restrict__ rofs, int* __restrict__ rend) {
  __shared__ int lhist[BNODES];
  __shared__ int lofs[BNODES];
  __shared__ int lcur[BNODES];
  __shared__ int ss[256];
  int b = blockIdx.x;
  int t = threadIdx.x;
  int k0 = b * CAP;
  int ecnt = cursor[b];
  if (ecnt > CAP) ecnt = CAP;

  if (t < BNODES) lhist[t] = 0;
  __syncthreads();
  for (int k = t; k < ecnt; k += 256)
    atomicAdd(&lhist[pay[k0 + k] >> SRC_BITS], 1);
  __syncthreads();

  int own = (t < BNODES) ? lhist[t] : 0;
  ss[t] = own;
  __syncthreads();
  for (int off = 1; off < 256; off <<= 1) {
    int a0 = (t >= off) ? ss[t - off] : 0;
    __syncthreads();
    ss[t] += a0;
    __syncthreads();
  }
  if (t < BNODES) {
    int ex = ss[t] - own;
    lofs[t] = ex;
    lcur[t] = 0;
    rofs[b * BNODES + t] = k0 + ex;
    rend[b * BNODES + t] = k0 + ex + own;
  }
  __syncthreads();

  for (int k = t; k < ecnt; k += 256) {
    unsigned p = pay[k0 + k];
    int ld = p >> SRC_BITS;
    int r = atomicAdd(&lcur[ld], 1);
    srt[k0 + lofs[ld] + r] = (int)(p & SRC_MASK);
  }
}

// ---------------------------------------------------------------------------
// Fused HALF-bucket layer (round-0 structure; ONLY the gather inner loop
// changed): manual 4-deep software pipeline with two independent accumulator
// banks -> 4 loads in flight per thread before any consumption (MLP lever).
// 5 consecutive threads share a node (same cacheline per iteration -> TA
// coalesces); plain LDS stores into padded acc.
// ---------------------------------------------------------------------------
template<int DIN>
__global__ __launch_bounds__(512) void bucket_layer_kernel(
    const unsigned short* __restrict__ hin, const int* __restrict__ srt,
    const int* __restrict__ rofs, const int* __restrict__ rend,
    const float* __restrict__ Wrel, const float* __restrict__ bias,
    const float* __restrict__ Wroot, unsigned short* __restrict__ hout) {
  constexpr int AST = (DIN == 10) ? 11 : 21;
  constexpr int CH = DIN / 5;
  __shared__ int sSrc[SCAP];
  __shared__ float acc[HB * AST];
  __shared__ unsigned short roots[HB * DIN];
  __shared__ float sWrel[DIN * HH];
  __shared__ float sWroot[DIN * HH];
  __shared__ float sb[HH];
  __shared__ int sRofs[HB];
  __shared__ int sRend[HB];
  __shared__ int sSeg0, sSegLen;
  int b2 = blockIdx.x;
  int t = threadIdx.x;
  int nbase = b2 * HB;

  for (int i = t; i < DIN * HH; i += 512) {
    sWrel[i] = Wrel[i];
    sWroot[i] = Wroot[i];
  }
  if (t < HH) sb[t] = bias[t];
  if (t < HB) {
    sRofs[t] = rofs[nbase + t];
    sRend[t] = rend[nbase + t];
  }
  if (t == 0) {
    int s0 = rofs[nbase];
    int sl = rend[nbase + HB - 1] - s0;
    sSeg0 = s0;
    sSegLen = sl < SCAP ? sl : SCAP;
  }
  {
    const unsigned* rs = (const unsigned*)(hin + (size_t)nbase * DIN);
    unsigned* rd = (unsigned*)roots;
    for (int i = t; i < HB * DIN / 2; i += 512) rd[i] = rs[i];
  }
  __syncthreads();

  int seg0 = sSeg0, seglen = sSegLen;
  for (int i = t; i < seglen; i += 512) sSrc[i] = srt[seg0 + i];
  __syncthreads();

  if (t < HB * 5) {
    int ln = t / 5;
    int c = t - ln * 5;
    int k0 = sRofs[ln] - seg0;
    int k1 = sRend[ln] - seg0;
    if (k1 > seglen) k1 = seglen;  // >9-sigma clamp, never in practice
    const unsigned short* xb = hin + c * CH;
    if (CH == 4) {
      float a0 = 0, a1 = 0, a2 = 0, a3 = 0;
      float b0 = 0, b1 = 0, b2 = 0, b3 = 0;
      int k = k0;
      for (; k + 3 < k1; k += 4) {
        int s0 = sSrc[k], s1 = sSrc[k + 1], s2 = sSrc[k + 2], s3 = sSrc[k + 3];
        uint2 u0 = *(const uint2*)(xb + (size_t)s0 * DIN);
        uint2 u1 = *(const uint2*)(xb + (size_t)s1 * DIN);
        uint2 u2 = *(const uint2*)(xb + (size_t)s2 * DIN);
        uint2 u3 = *(const uint2*)(xb + (size_t)s3 * DIN);
        a0 += bflo(u0.x); a1 += bfhi(u0.x); a2 += bflo(u0.y); a3 += bfhi(u0.y);
        b0 += bflo(u1.x); b1 += bfhi(u1.x); b2 += bflo(u1.y); b3 += bfhi(u1.y);
        a0 += bflo(u2.x); a1 += bfhi(u2.x); a2 += bflo(u2.y); a3 += bfhi(u2.y);
        b0 += bflo(u3.x); b1 += bfhi(u3.x); b2 += bflo(u3.y); b3 += bfhi(u3.y);
      }
      for (; k < k1; k++) {
        uint2 u = *(const uint2*)(xb + (size_t)sSrc[k] * DIN);
        a0 += bflo(u.x); a1 += bfhi(u.x); a2 += bflo(u.y); a3 += bfhi(u.y);
      }
      float* a = acc + ln * AST + c * CH;
      a[0] = a0 + b0; a[1] = a1 + b1; a[2] = a2 + b2; a[3] = a3 + b3;
    } else {
      float a0 = 0, a1 = 0;
      float b0 = 0, b1 = 0;
      int k = k0;
      for (; k + 3 < k1; k += 4) {
        int s0 = sSrc[k], s1 = sSrc[k + 1], s2 = sSrc[k + 2], s3 = sSrc[k + 3];
        unsigned u0 = *(const unsigned*)(xb + (size_t)s0 * DIN);
        unsigned u1 = *(const unsigned*)(xb + (size_t)s1 * DIN);
        unsigned u2 = *(const unsigned*)(xb + (size_t)s2 * DIN);
        unsigned u3 = *(const unsigned*)(xb + (size_t)s3 * DIN);
        a0 += bflo(u0); a1 += bfhi(u0);
        b0 += bflo(u1); b1 += bfhi(u1);
        a0 += bflo(u2); a1 += bfhi(u2);
        b0 += bflo(u3); b1 += bfhi(u3);
      }
      for (; k < k1; k++) {
        unsigned u = *(const unsigned*)(xb + (size_t)sSrc[k] * DIN);
        a0 += bflo(u); a1 += bfhi(u);
      }
      float* a = acc + ln * AST + c * CH;
      a[0] = a0 + b0; a[1] = a1 + b1;
    }
  }
  __syncthreads();

  for (int idx = t; idx < HB * HH; idx += 512) {
    int ln = idx / HH;
    int j = idx - ln * HH;
    const float* a = acc + ln * AST;
    const unsigned short* r = roots + ln * DIN;
    float v = sb[j];
#pragma unroll
    for (int f = 0; f < DIN; f++) {
      v += a[f] * sWrel[f * HH + j];
      v += bflo((unsigned)r[f]) * sWroot[f * HH + j];
    }
    hout[(size_t)nbase * HH + idx] = f2bf(fmaxf(v, 0.0f));
  }
}

// ---------------------------------------------------------------------------
// Layer 3 + pooling (round-0 structure; gather inner loop pipelined 4-deep):
// dense into registers then written over acc (dead), then block-local pool +
// few global atomics. Post-ReLU >= 0 -> int atomicMax on float bits is
// order-correct; zero init reproduces where(cnt>0, max, 0).
// ---------------------------------------------------------------------------
__global__ __launch_bounds__(512) void bucket_layer_pool_kernel(
    const unsigned short* __restrict__ hin, const int* __restrict__ srt,
    const int* __restrict__ rofs, const int* __restrict__ rend,
    const float* __restrict__ Wrel, const float* __restrict__ bias,
    const float* __restrict__ Wroot, const int* __restrict__ batch,
    float* __restrict__ sump, int* __restrict__ maxp,
    float* __restrict__ cnt) {
  constexpr int DIN = 20;
  constexpr int AST = 21;
  __shared__ int sSrc[SCAP];
  __shared__ float acc[HB * AST];
  __shared__ unsigned short roots[HB * DIN];
  __shared__ int sBatch[HB];
  __shared__ float sWrel[DIN * HH];
  __shared__ float sWroot[DIN * HH];
  __shared__ float sb[HH];
  __shared__ int sRofs[HB];
  __shared__ int sRend[HB];
  __shared__ int sSeg0, sSegLen;
  int b2 = blockIdx.x;
  int t = threadIdx.x;
  int nbase = b2 * HB;

  for (int i = t; i < DIN * HH; i += 512) {
    sWrel[i] = Wrel[i];
    sWroot[i] = Wroot[i];
  }
  if (t < HH) sb[t] = bias[t];
  if (t < HB) {
    sRofs[t] = rofs[nbase + t];
    sRend[t] = rend[nbase + t];
    sBatch[t] = batch[nbase + t];
  }
  if (t == 0) {
    int s0 = rofs[nbase];
    int sl = rend[nbase + HB - 1] - s0;
    sSeg0 = s0;
    sSegLen = sl < SCAP ? sl : SCAP;
  }
  {
    const unsigned* rs = (const unsigned*)(hin + (size_t)nbase * DIN);
    unsigned* rd = (unsigned*)roots;
    for (int i = t; i < HB * DIN / 2; i += 512) rd[i] = rs[i];
  }
  __syncthreads();

  int seg0 = sSeg0, seglen = sSegLen;
  for (int i = t; i < seglen; i += 512) sSrc[i] = srt[seg0 + i];
  __syncthreads();

  if (t < HB * 5) {
    int ln = t / 5;
    int c = t - ln * 5;
    int k0 = sRofs[ln] - seg0;
    int k1 = sRend[ln] - seg0;
    if (k1 > seglen) k1 = seglen;
    const unsigned short* xb = hin + c * 4;
    float a0 = 0, a1 = 0, a2 = 0, a3 = 0;
    float b0 = 0, b1 = 0, b2 = 0, b3 = 0;
    int k = k0;
    for (; k + 3 < k1; k += 4) {
      int s0 = sSrc[k], s1 = sSrc[k + 1], s2 = sSrc[k + 2], s3 = sSrc[k + 3];
      uint2 u0 = *(const uint2*)(xb + (size_t)s0 * 20);
      uint2 u1 = *(const uint2*)(xb + (size_t)s1 * 20);
      uint2 u2 = *(const uint2*)(xb + (size_t)s2 * 20);
      uint2 u3 = *(const uint2*)(xb + (size_t)s3 * 20);
      a0 += bflo(u0.x); a1 += bfhi(u0.x); a2 += bflo(u0.y); a3 += bfhi(u0.y);
      b0 += bflo(u1.x); b1 += bfhi(u1.x); b2 += bflo(u1.y); b3 += bfhi(u1.y);
      a0 += bflo(u2.x); a1 += bfhi(u2.x); a2 += bflo(u2.y); a3 += bfhi(u2.y);
      b0 += bflo(u3.x); b1 += bfhi(u3.x); b2 += bflo(u3.y); b3 += bfhi(u3.y);
    }
    for (; k < k1; k++) {
      uint2 u = *(const uint2*)(xb + (size_t)sSrc[k] * 20);
      a0 += bflo(u.x); a1 += bfhi(u.x); a2 += bflo(u.y); a3 += bfhi(u.y);
    }
    float* a = acc + ln * AST + c * 4;
    a[0] = a0 + b0; a[1] = a1 + b1; a[2] = a2 + b2; a[3] = a3 + b3;
  }
  __syncthreads();

  float vreg[4];
#pragma unroll
  for (int u = 0; u < 4; u++) {
    int idx = t + u * 512;
    if (idx < HB * HH) {
      int ln = idx / HH;
      int j = idx - ln * HH;
      const float* a = acc + ln * AST;
      const unsigned short* r = roots + ln * DIN;
      float v = sb[j];
#pragma unroll
      for (int f = 0; f < DIN; f++) {
        v += a[f] * sWrel[f * HH + j];
        v += bflo((unsigned)r[f]) * sWroot[f * HH + j];
      }
      vreg[u] = fmaxf(v, 0.0f);
    }
  }
  __syncthreads();
#pragma unroll
  for (int u = 0; u < 4; u++) {
    int idx = t + u * 512;
    if (idx < HB * HH) {
      int ln = idx / HH;
      int j = idx - ln * HH;
      acc[ln * AST + j] = vreg[u];
    }
  }
  __syncthreads();

  int g0 = sBatch[0];
  int g1 = sBatch[HB - 1];
  int ngr = g1 - g0 + 1;
  for (int it = t; it < ngr * HH; it += 512) {
    int gi = it / HH;
    int j = it - gi * HH;
    int g = g0 + gi;
    float s = 0.0f, m = 0.0f;
    int c = 0;
    for (int ln = 0; ln < HB; ln++) {
      if (sBatch[ln] == g) {
        float v = acc[ln * AST + j];
        s += v;
        m = fmaxf(m, v);
        c++;
      }
    }
    if (c) {
      atomicAdd(&sump[g * HH + j], s);
      atomicMax(&maxp[g * HH + j], __float_as_int(m));
      if (j == 0) atomicAdd(&cnt[g], (float)c);
    }
  }
}

__global__ __launch_bounds__(256) void readout_kernel(
    const float* __restrict__ sump, const int* __restrict__ maxp,
    const float* __restrict__ cnt, const float* __restrict__ Wlin,
    const float* __restrict__ blin, float* __restrict__ out) {
  int idx = blockIdx.x * 256 + threadIdx.x;
  if (idx >= GG * LL) return;
  int g = idx / LL;
  int l = idx - g * LL;
  float c = cnt[g];
  float inv = 1.0f / fmaxf(c, 1.0f);
  float acc = blin[l];
#pragma unroll
  for (int j = 0; j < HH; j++) {
    float mx = __int_as_float(maxp[g * HH + j]);
    float mean = sump[g * HH + j] * inv;
    acc += mx * Wlin[j * LL + l];
    acc += mean * Wlin[(HH + j) * LL + l];
  }
  out[idx] = acc;
}

extern "C" void kernel_launch(void* const* d_in, const int* in_sizes, int n_in,
                              void* d_out, int out_size, void* d_ws,
                              size_t ws_size, hipStream_t stream) {
  const float* x = (const float*)d_in[0];
  const int* edge_index = (const int*)d_in[1];
  const int* batch = (const int*)d_in[2];
  const float* W_rel1 = (const float*)d_in[3];
  const float* b1 = (const float*)d_in[4];
  const float* W_root1 = (const float*)d_in[5];
  const float* W_rel2 = (const float*)d_in[6];
  const float* b2 = (const float*)d_in[7];
  const float* W_root2 = (const float*)d_in[8];
  const float* W_rel3 = (const float*)d_in[9];
  const float* b3 = (const float*)d_in[10];
  const float* W_root3 = (const float*)d_in[11];
  const float* W_lin = (const float*)d_in[12];
  const float* b_lin = (const float*)d_in[13];
  float* out = (float*)d_out;

  const int E = in_sizes[1] / 2;
  const int n_nodes = in_sizes[0] / FF;  // == NN
  const int* src = edge_index;
  const int* dst = edge_index + E;

  // Workspace layout (16B-aligned chunks)
  unsigned int* pay = (unsigned int*)d_ws;       // NB*CAP u32 (14.3MB)
  int* srt = (int*)(pay + (size_t)NB * CAP);     // NB*CAP (14.3MB)
  int* rofs = srt + (size_t)NB * CAP;            // NN
  int* rend = rofs + NN;                         // NN
  int* cursor = rend + NN;                       // 512
  float* sump = (float*)(cursor + 512);          // GG*HH
  int* maxp = (int*)(sump + GG * HH);            // GG*HH
  float* cnt = (float*)(maxp + GG * HH);         // 512
  unsigned short* xb = (unsigned short*)(cnt + 512);  // NN*FF bf16 (2MB)
  unsigned short* h1 = xb + (size_t)NN * FF;     // NN*HH bf16 (4MB)
  unsigned short* h2 = h1 + (size_t)NN * HH;     // NN*HH bf16 (4MB)

  const int edge_tiles = (E + TILE - 1) / TILE;

  // ---- Cast x to bf16 + zero cursors/pool accumulators ----
  cast_init_kernel<<<(n_nodes * FF + 255) / 256, 256, 0, stream>>>(
      x, xb, sump, maxp, cnt, cursor, n_nodes * FF);

  // ---- Edge partition + one-time CSR build ----
  multisplit_kernel<<<edge_tiles, 512, 0, stream>>>(src, dst, cursor, pay, E);
  bucket_csr_kernel<<<NB, 256, 0, stream>>>(pay, cursor, srt, rofs, rend);

  // ---- Fused per-half-bucket layers (4-deep pipelined gather) ----
  bucket_layer_kernel<FF><<<NB * 2, 512, 0, stream>>>(
      xb, srt, rofs, rend, W_rel1, b1, W_root1, h1);
  bucket_layer_kernel<HH><<<NB * 2, 512, 0, stream>>>(
      h1, srt, rofs, rend, W_rel2, b2, W_root2, h2);
  bucket_layer_pool_kernel<<<NB * 2, 512, 0, stream>>>(
      h2, srt, rofs, rend, W_rel3, b3, W_root3, batch, sump, maxp, cnt);

  // ---- Readout ----
  readout_kernel<<<(GG * LL + 255) / 256, 256, 0, stream>>>(
      sump, maxp, cnt, W_lin, b_lin, out);
}